// Round 1
// baseline (364.108 us; speedup 1.0000x reference)
//
#include <hip/hip_runtime.h>
#include <hip/hip_bf16.h>

// CubicBSplineFFD: v (4,3,42,42,42) f32 -> out (4,3,192,192,192) f32.
// Closed form after collapsing the 3 stride-5 transposed convs + crop(5,197):
//   out[m] = sum_{d=0..3} B_d(r/5) * v[a+d],  a = m/5, r = m%5   (per axis)
// Derivation (verified): kernel index i = 5d + 4 - r; weights
//   d=0: B(1+f)=(1-f)^3/6, d=1: B(f), d=2: B(1-f), d=3: B(2-f)=f^3/6, f=r/5.
// All control indices a..a+3 are in [0,42) for m in [0,192): no bounds logic.
//
// R1 change vs 394us baseline: phase B no longer issues stride-5 scalar
// global stores (20-line-span wave stores, 5x write-request amplification).
// Cell results go to an LDS z-buffer (overlaid on dead vt/t1 pool, chunked
// 16+16+7 cells to fit 80-float rows), then a coalesced float4 write-out
// pass stores 1024B dense per wave instruction.

#define CPN 42      // control points per dim
#define IMG 192
#define TXX 6       // x tile
#define TYY 6       // y tile
#define NCX 5       // control pts needed in x for a 6-wide tile
#define NCY 5
#define NCZ 42      // full z control range
#define SXS 44      // padded row stride for sxy
#define NTHREADS 256
#define ZBS 80      // z-buffer row stride in floats (320 B, 16B-aligned)
#define POOLF (TXX * TYY * ZBS)   // 2880 floats; overlays vt(1050)+t1(1260)

struct WTabC { double w[5][4]; };
constexpr WTabC make_wb() {
  WTabC t{};
  for (int r = 0; r < 5; ++r) {
    double f = (double)r / 5.0;
    double g = (double)(5 - r) / 5.0;      // 1 - f
    t.w[r][0] = g * g * g / 6.0;                       // B(1+f)
    t.w[r][1] = 2.0 / 3.0 + (0.5 * f - 1.0) * f * f;   // B(f)
    t.w[r][2] = 2.0 / 3.0 + (0.5 * g - 1.0) * g * g;   // B(1-f)
    t.w[r][3] = f * f * f / 6.0;                       // B(2-f)
  }
  return t;
}
constexpr WTabC WB = make_wb();

__device__ __forceinline__ float bsp_w_rt(int r, int d) {
  double f = (double)r / 5.0;
  double g = (double)(5 - r) / 5.0;
  double w;
  if (d == 0)      { w = g * g * g / 6.0; }
  else if (d == 1) { w = 2.0 / 3.0 + (0.5 * f - 1.0) * f * f; }
  else if (d == 2) { w = 2.0 / 3.0 + (0.5 * g - 1.0) * g * g; }
  else             { w = f * f * f / 6.0; }
  return (float)w;
}

// One z-chunk: compute cells [CB, CB+NC) into the LDS z-buffer, barrier,
// then store NQ float4 per (xi,yi) row with fully-coalesced lanes.
// z range stored: [CB*5, CB*5 + 4*NQ). Computed-but-unstored tail (z>=192)
// simply stays in LDS.
template <int CB, int NC, int NQ>
__device__ __forceinline__ void z_chunk(const float* sxy_, float* zbuf,
                                        float* op, int x0, int y0, int tid) {
  for (int j = tid; j < TXX * TYY * NC; j += NTHREADS) {
    int cc = j % NC;                       // cell within chunk
    int xy = j / NC;
    const float* sp = &sxy_[xy * SXS + CB + cc];
    float f0 = sp[0], f1 = sp[1], f2 = sp[2], f3 = sp[3];
    float* zp = &zbuf[xy * ZBS + 5 * cc];  // lane stride 5 over 32 banks: free
#pragma unroll
    for (int r = 0; r < 5; ++r) {
      zp[r] = (float)WB.w[r][0] * f0 + (float)WB.w[r][1] * f1
            + (float)WB.w[r][2] * f2 + (float)WB.w[r][3] * f3;
    }
  }
  __syncthreads();
  for (int l = tid; l < TXX * TYY * NQ; l += NTHREADS) {
    int q = l % NQ;
    int xy = l / NQ;
    int yi = xy % TYY;
    int xi = xy / TYY;
    const float4 val =
        *reinterpret_cast<const float4*>(&zbuf[xy * ZBS + 4 * q]);
    float* dst = op + ((size_t)((x0 + xi) * IMG + (y0 + yi)) * IMG
                       + CB * 5 + 4 * q);
    *reinterpret_cast<float4*>(dst) = val;  // 64 lanes x 16B dense
  }
}

__global__ void __launch_bounds__(NTHREADS) ffd_kernel(
    const float* __restrict__ v, float* __restrict__ out) {
  const int tid = threadIdx.x;
  const int bx = blockIdx.x;   // x tile index (0..31)
  const int by = blockIdx.y;   // y tile index (0..31)
  const int sl = blockIdx.z;   // fused (batch, dim) slice (0..11)

  const int x0 = bx * TXX;
  const int y0 = by * TYY;
  const int cx0 = x0 / 5;      // first control index needed in x (<= 37)
  const int cy0 = y0 / 5;

  __shared__ float wtab[20];                          // runtime weight table
  __shared__ __align__(16) float sxy[TXX * TYY * SXS]; // 1584 f: xy-convolved
  __shared__ __align__(16) float pool[POOLF];          // 2880 f: vt+t1 / zbuf
  float* vt = pool;                   // 1050 f: staged control points
  float* t1 = pool + NCX * NCY * NCZ; // 1260 f: y-convolved (ends at 2310)

  if (tid < 20) wtab[tid] = bsp_w_rt(tid >> 2, tid & 3);

  // ---- stage v tile: 5 x 5 x 42 control points ----
  const float* vs = v + (size_t)sl * (CPN * CPN * CPN);
  for (int l = tid; l < NCX * NCY * NCZ; l += NTHREADS) {
    int cz = l % NCZ;
    int rest = l / NCZ;
    int cy = rest % NCY;
    int cx = rest / NCY;
    vt[l] = vs[((cx0 + cx) * CPN + (cy0 + cy)) * CPN + cz];
  }
  __syncthreads();

  // ---- A1: convolve along y -> t1[yi][cx][cz] ----
  for (int l = tid; l < TYY * NCX * NCZ; l += NTHREADS) {
    int cz = l % NCZ;
    int rest = l / NCZ;
    int cx = rest % NCX;
    int yi = rest / NCX;
    int y = y0 + yi;
    int ay = y / 5;
    int ry = y - 5 * ay;
    int cyo = ay - cy0;                      // 0 or 1
    const float* wr = &wtab[ry * 4];
    const float* vp = &vt[(cx * NCY + cyo) * NCZ + cz];
    float acc = wr[0] * vp[0] + wr[1] * vp[NCZ]
              + wr[2] * vp[2 * NCZ] + wr[3] * vp[3 * NCZ];
    t1[(yi * NCX + cx) * NCZ + cz] = acc;
  }
  __syncthreads();

  // ---- A2: convolve along x -> sxy[xi*TYY+yi][cz] ----
  for (int l = tid; l < TXX * TYY * NCZ; l += NTHREADS) {
    int cz = l % NCZ;
    int rest = l / NCZ;
    int yi = rest % TYY;
    int xi = rest / TYY;
    int x = x0 + xi;
    int ax = x / 5;
    int rx = x - 5 * ax;
    int cxo = ax - cx0;                      // 0 or 1
    const float* wr = &wtab[rx * 4];
    const float* tp = &t1[(yi * NCX + cxo) * NCZ + cz];
    float acc = wr[0] * tp[0] + wr[1] * tp[NCZ]
              + wr[2] * tp[2 * NCZ] + wr[3] * tp[3 * NCZ];
    sxy[(xi * TYY + yi) * SXS + cz] = acc;
  }
  __syncthreads();                           // vt/t1 dead from here: pool=zbuf

  // ---- B: z-conv per 5-output cell into LDS zbuf, then coalesced f4 store.
  // Chunks: cells [0,16) -> z [0,80); [16,32) -> z [80,160);
  //         [32,39) -> z [160,195), store z [160,192).
  float* op = out + (size_t)sl * (IMG * IMG * IMG);
  z_chunk<0, 16, 20>(sxy, pool, op, x0, y0, tid);
  __syncthreads();                           // zbuf reuse hazard
  z_chunk<16, 16, 20>(sxy, pool, op, x0, y0, tid);
  __syncthreads();
  z_chunk<32, 7, 8>(sxy, pool, op, x0, y0, tid);
}

extern "C" void kernel_launch(void* const* d_in, const int* in_sizes, int n_in,
                              void* d_out, int out_size, void* d_ws, size_t ws_size,
                              hipStream_t stream) {
  (void)in_sizes; (void)n_in; (void)d_ws; (void)ws_size; (void)out_size;
  const float* v = (const float*)d_in[0];
  float* out = (float*)d_out;
  dim3 grid(IMG / TXX, IMG / TYY, 12);   // 32 x 32 x 12
  ffd_kernel<<<grid, NTHREADS, 0, stream>>>(v, out);
}